// Round 4
// baseline (1927.704 us; speedup 1.0000x reference)
//
#include <hip/hip_runtime.h>

// AdEx Euler integration, fp32 port of the jax/numpy reference.
// T=40000 sequential steps; N=1024 neurons -> 16 producer waves on 16 CUs.
//
// MODEL: lone in-order wave issues ~1 instr / 6.1 cyc + ~12 cyc/step fixed
// residual (exp chain + per-buffer drains). Fit: R14 98 cyc/step @14.1
// slots, R17 81 cyc/step @11.3 slots. Dispatch-slot bound -> only lever is
// fewer producer slots.
// R15: C-level reg arrays got SUNK (wash). R16: AD via LDS = lgkm
//      serialization + bank conflicts (2264us). R17: UNSINKABLE volatile-asm
//      global_load_dwordx2 double-buffer + ds_write_b64 staging -> 1354us.
//
// R18 (this): two residual slot cuts, math DAG untouched:
//   - spike branch-out: if(__ballot(sp)) {selects}  (cold path; ~98% of
//     steps skip wns-add + 2 cndmasks). Construct ran in R16 with absmax
//     EXACTLY 4.882812e-04 -> proven bit-exact.
//   - AD loads widened to global_load_dwordx4 (16/buffer): 0.5 -> 0.25... 
//     1 -> 0.5 slots/step. Quad lo/hi v2f halves are even-aligned subregs;
//     shufflevector extraction expected zero-mov (worst case: wash).
//     vmcnt(32) -> vmcnt(16).
// ~9.8 slots/step -> ~72 cyc/step -> predict kernel 1160-1250 us.

typedef float v2f __attribute__((ext_vector_type(2)));
typedef float v4f __attribute__((ext_vector_type(4)));

__device__ __forceinline__ float exp2_raw(float u) {
    float r;
    asm("v_exp_f32 %0, %1" : "=v"(r) : "v"(u));   // r = 2^u, ~1 ulp
    return r;
}

// s_waitcnt lgkmcnt(0) (vmcnt max, expcnt max, lgkmcnt 0).
#define LGKM0() __builtin_amdgcn_s_waitcnt(0xC07F)

// ---------------------------------------------------------------------------
// Prep: AD[k] = {Ar2_k, delta} for k in [0, T+32). Bit-identical constant
// folding to the producer's original in-loop computation (same f64
// expressions, rounded once to f32; same fmaf on the same I value).
// ---------------------------------------------------------------------------
__global__ void __launch_bounds__(256) adex_prep_kernel(
    const float* __restrict__ I_ext,
    const float* __restrict__ p_V_rest,
    const float* __restrict__ p_R,
    const float* __restrict__ p_tau,
    const float* __restrict__ p_tau_w,
    const float* __restrict__ p_a,
    float2* __restrict__ AD, int T)
{
#pragma clang fp contract(off)
    int k = blockIdx.x * 256 + threadIdx.x;
    if (k >= T + 32) return;

    const float V_rest = *p_V_rest;
    const float R      = *p_R;
    const float tau    = *p_tau;
    const float tau_w  = *p_tau_w;
    const float a      = *p_a;
    const float dt     = 5e-5f;

    const double dcv = (double)dt / (double)tau;
    const double dcw = (double)dt / (double)tau_w;

    const float cRI   = (float)(dcv * (double)R);
    const float cVr2  = (float)(dcv * (double)V_rest);
    const float delta = (float)(-(double)a * dcw * (double)V_rest);

    int ki = (k <= T + 4) ? k : (T + 4);      // tail entries never consumed
    AD[k] = make_float2(fmaf(cRI, I_ext[ki], cVr2), delta);
}

// ---------------------------------------------------------------------------
// Main producer/consumer kernel.
// ---------------------------------------------------------------------------
__global__ void __launch_bounds__(128, 1) adex_pc_kernel(
    const float* __restrict__ V0,
    const float* __restrict__ w0,
    const float* __restrict__ p_V_reset,
    const float* __restrict__ p_V_T,
    const float* __restrict__ p_V_thres,
    const float* __restrict__ p_delta_T,
    const float* __restrict__ p_R,
    const float* __restrict__ p_tau,
    const float* __restrict__ p_tau_w,
    const float* __restrict__ p_a,
    const float* __restrict__ p_b,
    const float* __restrict__ ADf,       // workspace: {Ar2,delta} pairs
    float* __restrict__ out,
    int T, int N)
{
#pragma clang fp contract(off)
    // Ring of 4 buffers x 32 steps x 64 lanes x float2 = 64 KiB.
    // [buf][step][lane]: lane stride 8B -> ds b64 ops conflict-free
    // (16-lane phases each cover banks 0..31 exactly once; R17 measured 0).
    __shared__ v2f stage[4][32][64];
    __shared__ int flags[2];             // [0]=produced bufs, [1]=consumed

    const int tid   = threadIdx.x;
    const int l     = tid & 63;
    const int wave  = tid >> 6;
    const int nbase = blockIdx.x * 64;   // N % 64 == 0

    volatile int* vflags = (volatile int*)flags;
    if (tid < 2) flags[tid] = 0;
    __syncthreads();                     // once, at kernel start only

    const int NB = T >> 5;               // 32-step buffers (T % 64 == 0 -> NB even)

    if (wave == 0) {
        // ---------------- producer: the serial recurrence ----------------
        const float V_reset = *p_V_reset;
        const float V_T     = *p_V_T;
        const float V_thres = *p_V_thres;
        const float delta_T = *p_delta_T;
        const float R       = *p_R;
        const float tau     = *p_tau;
        const float tau_w   = *p_tau_w;
        const float a       = *p_a;
        const float b       = *p_b;
        const float dt      = 5e-5f;

        // Constants folded in f64, rounded once to f32 (bit-neutral class).
        const double dT  = (double)delta_T;
        const double dcv = (double)dt / (double)tau;
        const double dcw = (double)dt / (double)tau_w;
        const double l2e = 1.4426950408889634;

        const float c_exp = (float)(l2e / dT);
        const float c2    = (float)(log2(dT * dcv) - (double)V_T * (l2e / dT));
        const float alpha = (float)(1.0 - dcv);
        const float ncRv  = (float)(-dcv * (double)R);
        const float beta  = (float)(1.0 - dcw);
        const float gamma = (float)((double)a * dcw);

        // Packed coefficient pairs for v_pk_fma_f32.
        v2f cAG; cAG.x = alpha; cAG.y = gamma;
        v2f cNB; cNB.x = ncRv;  cNB.y = beta;

        // Packed state {V, w}.
        v2f VW;
        VW.x = V0[nbase + l];
        VW.y = w0[nbase + l];

        // AD double-buffer register sets: 16 quads each (64 VGPR/set),
        // defined only by volatile asm loads -> unsinkable, resident.
        v4f A[16], B[16];
        const unsigned long long adbase = (unsigned long long)ADf;

        // Issue one buffer's 32 {Ar2,delta} pairs as 16 dwordx4.
#define LDSET(ARR, VOFF)                                                  \
        {                                                                 \
            unsigned _vo = (VOFF);                                        \
            _Pragma("unroll")                                             \
            for (int j = 0; j < 16; ++j)                                  \
                asm volatile("global_load_dwordx4 %0, %1, %2 offset:%3"   \
                             : "=v"(ARR[j])                               \
                             : "v"(_vo), "s"(adbase), "n"(j * 16));       \
        }

        // One step. All fp ops value-identical to the verified R14 math:
        //   P1.lo = fma(alpha,V,Ar2)    P1.hi = fma(gamma,V,delta)
        //   VW.lo = fma(ncRv,w,P1.lo)   VW.hi = fma(beta,w,P1.hi)  (in-place)
        //   VW.x += 2^fma(V,c_exp,c2)
        // Spike fixup in a cold uniform branch (R16-proven bit-exact):
        // selects execute identical values when taken; no-ops otherwise.
#define ADEX_STEP(ADP, DST)                                               \
        {                                                                 \
            *(DST) = VW;                                                  \
            float u  = fmaf(VW.x, c_exp, c2);                             \
            bool  sp = VW.x > V_thres;                                    \
            float ex = exp2_raw(u);                                       \
            v2f P1;                                                       \
            asm("v_pk_fma_f32 %0, %1, %2, %3 op_sel:[0,0,0] op_sel_hi:[1,0,1]" \
                : "=v"(P1) : "v"(cAG), "v"(VW), "v"(ADP));                \
            asm("v_pk_fma_f32 %0, %1, %0, %2 op_sel:[0,1,0] op_sel_hi:[1,1,1]" \
                : "+v"(VW) : "v"(cNB), "v"(P1));                          \
            VW.x += ex;                                                   \
            if (__builtin_expect(__ballot(sp) != 0, 0)) {                 \
                VW.x = sp ? V_reset : VW.x;                               \
                VW.y = sp ? VW.y + b : VW.y;                              \
            }                                                             \
        }

        // One 32-step buffer from register set ARR. vmcnt(16): the newest
        // 16 loads (next buffer's set) stay in flight; ARR is resident.
        // sched_barrier stops reg-only asm hoisting past the wait (rule #18).
#define PRODUCE(ARR)                                                      \
        {                                                                 \
            asm volatile("s_waitcnt vmcnt(16)");                          \
            __builtin_amdgcn_sched_barrier(0);                            \
            v2f* sb = &stage[pi & 3][0][l];                               \
            _Pragma("unroll")                                             \
            for (int s = 0; s < 16; ++s) {                                \
                v4f q = ARR[s];                                           \
                v2f ad0 = __builtin_shufflevector(q, q, 0, 1);            \
                v2f ad1 = __builtin_shufflevector(q, q, 2, 3);            \
                ADEX_STEP(ad0, sb + (2 * s) * 64);                        \
                ADEX_STEP(ad1, sb + (2 * s + 1) * 64);                    \
            }                                                             \
            LGKM0();                                                      \
            asm volatile("" ::: "memory");                                \
            ++pi;                                                         \
            vflags[0] = pi;                                               \
        }

        // Prologue: buffer 0 into set A.
        LDSET(A, 0u);

        int pi = 0;
        unsigned voff = 0;
        while (pi < NB) {
            // Back-pressure every 2nd buffer: ring 4 deep; producing pi
            // needs consumed >= pi-3; checking >= pi-2 covers pi and pi+1.
            while (vflags[1] < pi - 2) __builtin_amdgcn_s_sleep(2);
            asm volatile("" ::: "memory");

            voff += 256;
            LDSET(B, voff);        // buffer pi+1
            PRODUCE(A);

            voff += 256;
            LDSET(A, voff);        // buffer pi+2 (last issue reads the
                                   // (T+32)-entry AD tail; never consumed)
            PRODUCE(B);
        }
#undef PRODUCE
#undef ADEX_STEP
#undef LDSET
    } else {
        // ---------------- consumer: drain LDS -> global ----------------
        float* __restrict__ outw = out + (size_t)T * N;
        unsigned idx = (unsigned)(nbase + l);      // += N per step

        for (int ci = 0; ci < NB; ++ci) {
            while (vflags[0] < ci + 1) __builtin_amdgcn_s_sleep(2);
            asm volatile("" ::: "memory");
            const v2f* cb = &stage[ci & 3][0][l];
#pragma unroll
            for (int s = 0; s < 32; ++s) {
                v2f q = cb[s * 64];
                out[idx]  = q.x;
                outw[idx] = q.y;
                idx += (unsigned)N;
            }
            // LDS reads retired (store data deps forced waits); slot free.
            asm volatile("" ::: "memory");
            vflags[1] = ci + 1;
        }
    }
}

// Fallback: R11-style single-wave kernel for shapes that don't meet the
// producer/consumer preconditions (N%64, T%64, workspace size).
__global__ void __launch_bounds__(64, 1) adex_fallback_kernel(
    const float* __restrict__ I_ext,
    const float* __restrict__ V0,
    const float* __restrict__ w0,
    const float* __restrict__ p_V_rest,
    const float* __restrict__ p_V_reset,
    const float* __restrict__ p_V_T,
    const float* __restrict__ p_V_thres,
    const float* __restrict__ p_delta_T,
    const float* __restrict__ p_R,
    const float* __restrict__ p_tau,
    const float* __restrict__ p_tau_w,
    const float* __restrict__ p_a,
    const float* __restrict__ p_b,
    float* __restrict__ out,
    int T, int N)
{
#pragma clang fp contract(off)
    const int l     = threadIdx.x;
    const int nbase = blockIdx.x * 64;
    int n = nbase + l;
    if (n >= N) n = N - 1;

    const float V_rest  = *p_V_rest;
    const float V_reset = *p_V_reset;
    const float V_T     = *p_V_T;
    const float V_thres = *p_V_thres;
    const float delta_T = *p_delta_T;
    const float R       = *p_R;
    const float tau     = *p_tau;
    const float tau_w   = *p_tau_w;
    const float a       = *p_a;
    const float b       = *p_b;
    const float dt      = 5e-5f;

    const double dT  = (double)delta_T;
    const double dcv = (double)dt / (double)tau;
    const double dcw = (double)dt / (double)tau_w;
    const double l2e = 1.4426950408889634;

    const float c_exp = (float)(l2e / dT);
    const float c2    = (float)(log2(dT * dcv) - (double)V_T * (l2e / dT));
    const float alpha = (float)(1.0 - dcv);
    const float ncRv  = (float)(-dcv * (double)R);
    const float beta  = (float)(1.0 - dcw);
    const float gamma = (float)((double)a * dcw);
    const float delta = (float)(-(double)a * dcw * (double)V_rest);
    const float cRI   = (float)(dcv * (double)R);
    const float cVr2  = (float)(dcv * (double)V_rest);

    float V = V0[n];
    float w = w0[n];

    float* outVb = out + nbase;
    float* outWb = out + (size_t)T * N + nbase;

#define ADEX_STEP(Ar2_k)                                            \
    {                                                               \
        outVb[l] = V;                                               \
        outWb[l] = w;                                               \
        outVb += N;                                                 \
        outWb += N;                                                 \
        float ex3 = exp2_raw(fmaf(V, c_exp, c2));                   \
        float m1  = fmaf(alpha, V, (Ar2_k));                        \
        float m2  = fmaf(ncRv, w, m1);                              \
        float Vn  = m2 + ex3;                                       \
        float t2  = fmaf(gamma, V, delta);                          \
        float wn  = fmaf(beta, w, t2);                              \
        bool  spike = V > V_thres;                                  \
        float wns = wn + b;                                         \
        Vn = spike ? V_reset : Vn;                                  \
        wn = spike ? wns : wn;                                      \
        V = Vn;                                                     \
        w = wn;                                                     \
    }

    float A[16], B[16];
#pragma unroll
    for (int j = 0; j < 16; ++j) A[j] = fmaf(cRI, I_ext[j], cVr2);

    for (int kb = 0; kb < T; kb += 32) {
#pragma unroll
        for (int j = 0; j < 16; ++j)
            B[j] = fmaf(cRI, I_ext[kb + 16 + j], cVr2);
#pragma unroll
        for (int j = 0; j < 16; ++j) ADEX_STEP(A[j]);
        {
            int pb = kb + 32;
            if (pb > T - 11) pb = T - 11;
#pragma unroll
            for (int j = 0; j < 16; ++j)
                A[j] = fmaf(cRI, I_ext[pb + j], cVr2);
        }
#pragma unroll
        for (int j = 0; j < 16; ++j) ADEX_STEP(B[j]);
    }
#undef ADEX_STEP
}

extern "C" void kernel_launch(void* const* d_in, const int* in_sizes, int n_in,
                              void* d_out, int out_size, void* d_ws, size_t ws_size,
                              hipStream_t stream) {
    const float* I_ext = (const float*)d_in[0];
    const float* V0    = (const float*)d_in[1];
    const float* w0    = (const float*)d_in[2];

    const int N = in_sizes[1];          // 1024 (multiple of 64)
    const int T = out_size / (2 * N);   // 40000 (multiple of 64)

    const size_t ws_need = (size_t)(T + 32) * sizeof(float2);

    if ((N % 64 == 0) && (T % 64 == 0) && d_ws != nullptr && ws_size >= ws_need) {
        adex_prep_kernel<<<(T + 32 + 255) / 256, 256, 0, stream>>>(
            I_ext,
            (const float*)d_in[3],      // V_rest
            (const float*)d_in[8],      // R
            (const float*)d_in[9],      // tau
            (const float*)d_in[10],     // tau_w
            (const float*)d_in[11],     // a
            (float2*)d_ws, T);
        adex_pc_kernel<<<N / 64, 128, 0, stream>>>(
            V0, w0,
            (const float*)d_in[4],      // V_reset
            (const float*)d_in[5],      // V_T
            (const float*)d_in[6],      // V_thres
            (const float*)d_in[7],      // delta_T
            (const float*)d_in[8],      // R
            (const float*)d_in[9],      // tau
            (const float*)d_in[10],     // tau_w
            (const float*)d_in[11],     // a
            (const float*)d_in[12],     // b
            (const float*)d_ws,
            (float*)d_out, T, N);
    } else {
        adex_fallback_kernel<<<(N + 63) / 64, 64, 0, stream>>>(
            I_ext, V0, w0,
            (const float*)d_in[3], (const float*)d_in[4], (const float*)d_in[5],
            (const float*)d_in[6], (const float*)d_in[7], (const float*)d_in[8],
            (const float*)d_in[9], (const float*)d_in[10], (const float*)d_in[11],
            (const float*)d_in[12], (float*)d_out, T, N);
    }
}

// Round 5
// 1609.461 us; speedup vs baseline: 1.1977x; 1.1977x over previous
//
#include <hip/hip_runtime.h>

// AdEx Euler integration, fp32 port of the jax/numpy reference.
// T=40000 sequential steps; N=1024 neurons -> 16 producer waves on 16 CUs.
//
// MODEL: lone in-order wave issues ~1 instr / ~6 cyc + ~12 cyc/step fixed
// residual (drains + polls + exp bubble). Fit: R14 98 cyc/step @14.1 slots,
// R17 81 cyc/step @11.3 slots. Dispatch-slot bound.
// R15: C-level reg arrays got SUNK (wash). R16: AD via LDS = lgkm
//      serialization + bank conflicts (2264us). R17: UNSINKABLE volatile-asm
//      global_load_dwordx2 double-buffer + ds_write_b64 staging -> 1354us.
// R18: spike branch-out REGRESSED (1651us): per-step v_cmp->SGPR->s_cmp->
//      s_cbranch serializes the in-order wave (~+18 cyc/step) even when the
//      branch is never taken. Per-step uniform branches are banned.
//
// R19 (this): exact R17 producer math (proven 1354us), minus two stalls:
//   - no LGKM0 before the flag write: DS ops of a wave execute in order
//     (single in-order DS pipe), so the flag ds_write cannot pass the 32
//     staging ds_write_b64s. The explicit lgkmcnt(0) drain was redundant.
//     (absmax is the tripwire: if DS in-order is false, consumer reads
//     stale data and absmax moves -> restore LGKM0.)
//   - back-pressure poll latency hidden: flag pre-read issued BEFORE the
//     16-instr LDSET burst, compared after; ~120cyc LDS latency overlaps.
// Predict ~75-77 cyc/step -> kernel ~1260-1300us; absmax EXACTLY
// 4.882812e-04; conflicts 0.

typedef float v2f __attribute__((ext_vector_type(2)));
typedef unsigned long long u64;

__device__ __forceinline__ float exp2_raw(float u) {
    float r;
    asm("v_exp_f32 %0, %1" : "=v"(r) : "v"(u));   // r = 2^u, ~1 ulp
    return r;
}

// ---------------------------------------------------------------------------
// Prep: AD[k] = {Ar2_k, delta} for k in [0, T+32). Bit-identical constant
// folding to the producer's original in-loop computation (same f64
// expressions, rounded once to f32; same fmaf on the same I value).
// ---------------------------------------------------------------------------
__global__ void __launch_bounds__(256) adex_prep_kernel(
    const float* __restrict__ I_ext,
    const float* __restrict__ p_V_rest,
    const float* __restrict__ p_R,
    const float* __restrict__ p_tau,
    const float* __restrict__ p_tau_w,
    const float* __restrict__ p_a,
    float2* __restrict__ AD, int T)
{
#pragma clang fp contract(off)
    int k = blockIdx.x * 256 + threadIdx.x;
    if (k >= T + 32) return;

    const float V_rest = *p_V_rest;
    const float R      = *p_R;
    const float tau    = *p_tau;
    const float tau_w  = *p_tau_w;
    const float a      = *p_a;
    const float dt     = 5e-5f;

    const double dcv = (double)dt / (double)tau;
    const double dcw = (double)dt / (double)tau_w;

    const float cRI   = (float)(dcv * (double)R);
    const float cVr2  = (float)(dcv * (double)V_rest);
    const float delta = (float)(-(double)a * dcw * (double)V_rest);

    int ki = (k <= T + 4) ? k : (T + 4);      // tail entries never consumed
    AD[k] = make_float2(fmaf(cRI, I_ext[ki], cVr2), delta);
}

// ---------------------------------------------------------------------------
// Main producer/consumer kernel.
// ---------------------------------------------------------------------------
__global__ void __launch_bounds__(128, 1) adex_pc_kernel(
    const float* __restrict__ V0,
    const float* __restrict__ w0,
    const float* __restrict__ p_V_reset,
    const float* __restrict__ p_V_T,
    const float* __restrict__ p_V_thres,
    const float* __restrict__ p_delta_T,
    const float* __restrict__ p_R,
    const float* __restrict__ p_tau,
    const float* __restrict__ p_tau_w,
    const float* __restrict__ p_a,
    const float* __restrict__ p_b,
    const float* __restrict__ ADf,       // workspace: {Ar2,delta} pairs
    float* __restrict__ out,
    int T, int N)
{
#pragma clang fp contract(off)
    // Ring of 4 buffers x 32 steps x 64 lanes x float2 = 64 KiB.
    // [buf][step][lane]: lane stride 8B -> ds b64 ops conflict-free
    // (R17 measured SQ_LDS_BANK_CONFLICT = 0).
    __shared__ v2f stage[4][32][64];
    __shared__ int flags[2];             // [0]=produced bufs, [1]=consumed

    const int tid   = threadIdx.x;
    const int l     = tid & 63;
    const int wave  = tid >> 6;
    const int nbase = blockIdx.x * 64;   // N % 64 == 0

    volatile int* vflags = (volatile int*)flags;
    if (tid < 2) flags[tid] = 0;
    __syncthreads();                     // once, at kernel start only

    const int NB = T >> 5;               // 32-step buffers (T % 64 == 0 -> NB even)

    if (wave == 0) {
        // ---------------- producer: the serial recurrence ----------------
        const float V_reset = *p_V_reset;
        const float V_T     = *p_V_T;
        const float V_thres = *p_V_thres;
        const float delta_T = *p_delta_T;
        const float R       = *p_R;
        const float tau     = *p_tau;
        const float tau_w   = *p_tau_w;
        const float a       = *p_a;
        const float b       = *p_b;
        const float dt      = 5e-5f;

        // Constants folded in f64, rounded once to f32 (bit-neutral class).
        const double dT  = (double)delta_T;
        const double dcv = (double)dt / (double)tau;
        const double dcw = (double)dt / (double)tau_w;
        const double l2e = 1.4426950408889634;

        const float c_exp = (float)(l2e / dT);
        const float c2    = (float)(log2(dT * dcv) - (double)V_T * (l2e / dT));
        const float alpha = (float)(1.0 - dcv);
        const float ncRv  = (float)(-dcv * (double)R);
        const float beta  = (float)(1.0 - dcw);
        const float gamma = (float)((double)a * dcw);

        // Packed coefficient pairs for v_pk_fma_f32.
        v2f cAG; cAG.x = alpha; cAG.y = gamma;
        v2f cNB; cNB.x = ncRv;  cNB.y = beta;

        // Packed state {V, w}.
        v2f VW;
        VW.x = V0[nbase + l];
        VW.y = w0[nbase + l];

        // AD double-buffer register sets. Constant-indexed in fully
        // unrolled loops -> SROA to 64 discrete u64 (128 VGPR), defined
        // only by volatile asm loads -> unsinkable, guaranteed resident.
        u64 A[32], B[32];
        const unsigned long long adbase = (unsigned long long)ADf;

        // Issue one buffer's 32 {Ar2,delta} pairs. voff uniform; offsets
        // are compile-time immediates.
#define LDSET(ARR, VOFF)                                                  \
        {                                                                 \
            unsigned _vo = (VOFF);                                        \
            _Pragma("unroll")                                             \
            for (int j = 0; j < 32; ++j)                                  \
                asm volatile("global_load_dwordx2 %0, %1, %2 offset:%3"   \
                             : "=v"(ARR[j])                               \
                             : "v"(_vo), "s"(adbase), "n"(j * 8));        \
        }

        // One step. All fp ops value-identical to the verified R14 math:
        //   P1.lo = fma(alpha,V,Ar2)    P1.hi = fma(gamma,V,delta)
        //   VW.lo = fma(ncRv,w,P1.lo)   VW.hi = fma(beta,w,P1.hi)  (in-place)
        //   VW.x += 2^fma(V,c_exp,c2);  unconditional spike selects
        // (NO per-step branch -- R18 lesson). Pre-step state staged first.

        // One 32-step buffer from register set ARR. vmcnt(32): the newest
        // 32 loads (next buffer's set) stay in flight; ARR is resident.
        // sched_barrier stops reg-only asm hoisting past the wait (#18).
        // NO LGKM0 before the flag write: DS pipe is in-order per wave,
        // the flag ds_write retires after all staging ds_write_b64s.
#define PRODUCE(ARR)                                                      \
        {                                                                 \
            asm volatile("s_waitcnt vmcnt(32)");                          \
            __builtin_amdgcn_sched_barrier(0);                            \
            v2f* sb = &stage[pi & 3][0][l];                               \
            _Pragma("unroll")                                             \
            for (int s = 0; s < 32; ++s) {                                \
                sb[s * 64] = VW;                                          \
                float u  = fmaf(VW.x, c_exp, c2);                         \
                bool  sp = VW.x > V_thres;                                \
                float ex = exp2_raw(u);                                   \
                v2f P1;                                                   \
                asm("v_pk_fma_f32 %0, %1, %2, %3 op_sel:[0,0,0] op_sel_hi:[1,0,1]" \
                    : "=v"(P1) : "v"(cAG), "v"(VW), "v"(ARR[s]));         \
                asm("v_pk_fma_f32 %0, %1, %0, %2 op_sel:[0,1,0] op_sel_hi:[1,1,1]" \
                    : "+v"(VW) : "v"(cNB), "v"(P1));                      \
                VW.x += ex;                                               \
                float wns = VW.y + b;                                     \
                VW.x = sp ? V_reset : VW.x;                               \
                VW.y = sp ? wns : VW.y;                                   \
            }                                                             \
            asm volatile("" ::: "memory");                                \
            ++pi;                                                         \
            vflags[0] = pi;                                               \
        }

        // Prologue: buffer 0 into set A.
        LDSET(A, 0u);

        int pi = 0;
        unsigned voff = 0;
        while (pi < NB) {
            // Back-pressure (ring 4 deep): producing pi and pi+1 needs
            // consumed >= pi-2. Pre-read the flag BEFORE the 16-instr
            // LDSET burst so the ~120cyc LDS latency overlaps load issue;
            // the volatile poll loop only runs if the consumer is behind.
            int fc = vflags[1];
            voff += 256;
            LDSET(B, voff);        // buffer pi+1
            if (fc < pi - 2) {
                while (vflags[1] < pi - 2) __builtin_amdgcn_s_sleep(2);
            }
            asm volatile("" ::: "memory");

            PRODUCE(A);

            voff += 256;
            LDSET(A, voff);        // buffer pi+2 (last issue reads the
                                   // (T+32)-entry AD tail; never consumed)
            PRODUCE(B);
        }
#undef PRODUCE
#undef LDSET
    } else {
        // ---------------- consumer: drain LDS -> global ----------------
        float* __restrict__ outw = out + (size_t)T * N;
        unsigned idx = (unsigned)(nbase + l);      // += N per step

        for (int ci = 0; ci < NB; ++ci) {
            while (vflags[0] < ci + 1) __builtin_amdgcn_s_sleep(2);
            asm volatile("" ::: "memory");
            const v2f* cb = &stage[ci & 3][0][l];
#pragma unroll
            for (int s = 0; s < 32; ++s) {
                v2f q = cb[s * 64];
                out[idx]  = q.x;
                outw[idx] = q.y;
                idx += (unsigned)N;
            }
            // LDS reads retired (store data deps forced waits); slot free.
            asm volatile("" ::: "memory");
            vflags[1] = ci + 1;
        }
    }
}

// Fallback: R11-style single-wave kernel for shapes that don't meet the
// producer/consumer preconditions (N%64, T%64, workspace size).
__global__ void __launch_bounds__(64, 1) adex_fallback_kernel(
    const float* __restrict__ I_ext,
    const float* __restrict__ V0,
    const float* __restrict__ w0,
    const float* __restrict__ p_V_rest,
    const float* __restrict__ p_V_reset,
    const float* __restrict__ p_V_T,
    const float* __restrict__ p_V_thres,
    const float* __restrict__ p_delta_T,
    const float* __restrict__ p_R,
    const float* __restrict__ p_tau,
    const float* __restrict__ p_tau_w,
    const float* __restrict__ p_a,
    const float* __restrict__ p_b,
    float* __restrict__ out,
    int T, int N)
{
#pragma clang fp contract(off)
    const int l     = threadIdx.x;
    const int nbase = blockIdx.x * 64;
    int n = nbase + l;
    if (n >= N) n = N - 1;

    const float V_rest  = *p_V_rest;
    const float V_reset = *p_V_reset;
    const float V_T     = *p_V_T;
    const float V_thres = *p_V_thres;
    const float delta_T = *p_delta_T;
    const float R       = *p_R;
    const float tau     = *p_tau;
    const float tau_w   = *p_tau_w;
    const float a       = *p_a;
    const float b       = *p_b;
    const float dt      = 5e-5f;

    const double dT  = (double)delta_T;
    const double dcv = (double)dt / (double)tau;
    const double dcw = (double)dt / (double)tau_w;
    const double l2e = 1.4426950408889634;

    const float c_exp = (float)(l2e / dT);
    const float c2    = (float)(log2(dT * dcv) - (double)V_T * (l2e / dT));
    const float alpha = (float)(1.0 - dcv);
    const float ncRv  = (float)(-dcv * (double)R);
    const float beta  = (float)(1.0 - dcw);
    const float gamma = (float)((double)a * dcw);
    const float delta = (float)(-(double)a * dcw * (double)V_rest);
    const float cRI   = (float)(dcv * (double)R);
    const float cVr2  = (float)(dcv * (double)V_rest);

    float V = V0[n];
    float w = w0[n];

    float* outVb = out + nbase;
    float* outWb = out + (size_t)T * N + nbase;

#define ADEX_STEP(Ar2_k)                                            \
    {                                                               \
        outVb[l] = V;                                               \
        outWb[l] = w;                                               \
        outVb += N;                                                 \
        outWb += N;                                                 \
        float ex3 = exp2_raw(fmaf(V, c_exp, c2));                   \
        float m1  = fmaf(alpha, V, (Ar2_k));                        \
        float m2  = fmaf(ncRv, w, m1);                              \
        float Vn  = m2 + ex3;                                       \
        float t2  = fmaf(gamma, V, delta);                          \
        float wn  = fmaf(beta, w, t2);                              \
        bool  spike = V > V_thres;                                  \
        float wns = wn + b;                                         \
        Vn = spike ? V_reset : Vn;                                  \
        wn = spike ? wns : wn;                                      \
        V = Vn;                                                     \
        w = wn;                                                     \
    }

    float A[16], B[16];
#pragma unroll
    for (int j = 0; j < 16; ++j) A[j] = fmaf(cRI, I_ext[j], cVr2);

    for (int kb = 0; kb < T; kb += 32) {
#pragma unroll
        for (int j = 0; j < 16; ++j)
            B[j] = fmaf(cRI, I_ext[kb + 16 + j], cVr2);
#pragma unroll
        for (int j = 0; j < 16; ++j) ADEX_STEP(A[j]);
        {
            int pb = kb + 32;
            if (pb > T - 11) pb = T - 11;
#pragma unroll
            for (int j = 0; j < 16; ++j)
                A[j] = fmaf(cRI, I_ext[pb + j], cVr2);
        }
#pragma unroll
        for (int j = 0; j < 16; ++j) ADEX_STEP(B[j]);
    }
#undef ADEX_STEP
}

extern "C" void kernel_launch(void* const* d_in, const int* in_sizes, int n_in,
                              void* d_out, int out_size, void* d_ws, size_t ws_size,
                              hipStream_t stream) {
    const float* I_ext = (const float*)d_in[0];
    const float* V0    = (const float*)d_in[1];
    const float* w0    = (const float*)d_in[2];

    const int N = in_sizes[1];          // 1024 (multiple of 64)
    const int T = out_size / (2 * N);   // 40000 (multiple of 64)

    const size_t ws_need = (size_t)(T + 32) * sizeof(float2);

    if ((N % 64 == 0) && (T % 64 == 0) && d_ws != nullptr && ws_size >= ws_need) {
        adex_prep_kernel<<<(T + 32 + 255) / 256, 256, 0, stream>>>(
            I_ext,
            (const float*)d_in[3],      // V_rest
            (const float*)d_in[8],      // R
            (const float*)d_in[9],      // tau
            (const float*)d_in[10],     // tau_w
            (const float*)d_in[11],     // a
            (float2*)d_ws, T);
        adex_pc_kernel<<<N / 64, 128, 0, stream>>>(
            V0, w0,
            (const float*)d_in[4],      // V_reset
            (const float*)d_in[5],      // V_T
            (const float*)d_in[6],      // V_thres
            (const float*)d_in[7],      // delta_T
            (const float*)d_in[8],      // R
            (const float*)d_in[9],      // tau
            (const float*)d_in[10],     // tau_w
            (const float*)d_in[11],     // a
            (const float*)d_in[12],     // b
            (const float*)d_ws,
            (float*)d_out, T, N);
    } else {
        adex_fallback_kernel<<<(N + 63) / 64, 64, 0, stream>>>(
            I_ext, V0, w0,
            (const float*)d_in[3], (const float*)d_in[4], (const float*)d_in[5],
            (const float*)d_in[6], (const float*)d_in[7], (const float*)d_in[8],
            (const float*)d_in[9], (const float*)d_in[10], (const float*)d_in[11],
            (const float*)d_in[12], (float*)d_out, T, N);
    }
}

// Round 6
// 1570.213 us; speedup vs baseline: 1.2277x; 1.0250x over previous
//
#include <hip/hip_runtime.h>

// AdEx Euler integration, fp32 port of the jax/numpy reference.
// T=40000 sequential steps; N=1024 neurons -> 16 producer waves on 16 CUs.
//
// MODEL (R1-R19): lone in-order wave issues ~1 slot / ~7.1 cyc; wall =
// slots/step. R14 98cyc @14.1 slots; R17 81cyc @11.3; R19 (no-LGKM0 +
// poll-hiding) only -1% -> stall-shaving exhausted, slot count is the
// only lever. Proven-out failures: C-level reg prefetch arrays get SUNK
// (R15); AD via LDS serializes on lgkmcnt (R16); per-step uniform branch
// = VALU->SGPR->SALU->branch hazard, +18cyc/step (R18, banned).
//
// R20 (this): staging pair-fused via ds_write2st64_b64.
//   - layout [buf][step][lane] has 512B step stride = exactly the st64
//     (64x8B) unit -> ONE instruction writes pre-states of steps 2s and
//     2s+1 at offset0:2s offset1:2s+1. Same byte addresses as R19's two
//     ds_write_b64 (bank conflicts measured 0). -0.5 slot/step.
//   - state ping-pong VWa/VWb (step A: VWa->VWb, stage {VWa,VWb}, step B:
//     VWb->VWa): pure register renaming, identical fp DAG -> absmax must
//     stay EXACTLY 4.882812e-04.
//   - s_setprio(3) on producer (T5: role-diverse waves; consumer has 3x
//     issue slack + fire-and-forget stores -> no starvation risk).
// Predict kernel ~1250-1300us; conflicts 0; VALUBusy >= 1.15%.

typedef float v2f __attribute__((ext_vector_type(2)));
typedef unsigned long long u64;

__device__ __forceinline__ float exp2_raw(float u) {
    float r;
    asm("v_exp_f32 %0, %1" : "=v"(r) : "v"(u));   // r = 2^u, ~1 ulp
    return r;
}

// ---------------------------------------------------------------------------
// Prep: AD[k] = {Ar2_k, delta} for k in [0, T+32). Bit-identical constant
// folding to the producer's original in-loop computation (same f64
// expressions, rounded once to f32; same fmaf on the same I value).
// ---------------------------------------------------------------------------
__global__ void __launch_bounds__(256) adex_prep_kernel(
    const float* __restrict__ I_ext,
    const float* __restrict__ p_V_rest,
    const float* __restrict__ p_R,
    const float* __restrict__ p_tau,
    const float* __restrict__ p_tau_w,
    const float* __restrict__ p_a,
    float2* __restrict__ AD, int T)
{
#pragma clang fp contract(off)
    int k = blockIdx.x * 256 + threadIdx.x;
    if (k >= T + 32) return;

    const float V_rest = *p_V_rest;
    const float R      = *p_R;
    const float tau    = *p_tau;
    const float tau_w  = *p_tau_w;
    const float a      = *p_a;
    const float dt     = 5e-5f;

    const double dcv = (double)dt / (double)tau;
    const double dcw = (double)dt / (double)tau_w;

    const float cRI   = (float)(dcv * (double)R);
    const float cVr2  = (float)(dcv * (double)V_rest);
    const float delta = (float)(-(double)a * dcw * (double)V_rest);

    int ki = (k <= T + 4) ? k : (T + 4);      // tail entries never consumed
    AD[k] = make_float2(fmaf(cRI, I_ext[ki], cVr2), delta);
}

// ---------------------------------------------------------------------------
// Main producer/consumer kernel.
// ---------------------------------------------------------------------------
__global__ void __launch_bounds__(128, 1) adex_pc_kernel(
    const float* __restrict__ V0,
    const float* __restrict__ w0,
    const float* __restrict__ p_V_reset,
    const float* __restrict__ p_V_T,
    const float* __restrict__ p_V_thres,
    const float* __restrict__ p_delta_T,
    const float* __restrict__ p_R,
    const float* __restrict__ p_tau,
    const float* __restrict__ p_tau_w,
    const float* __restrict__ p_a,
    const float* __restrict__ p_b,
    const float* __restrict__ ADf,       // workspace: {Ar2,delta} pairs
    float* __restrict__ out,
    int T, int N)
{
#pragma clang fp contract(off)
    // Ring of 4 buffers x 32 steps x 64 lanes x float2 = 64 KiB.
    // [buf][step][lane]: lane stride 8B (conflict-free, R17/R19 measured 0);
    // step stride 512B = the ds_*st64 b64 unit.
    __shared__ v2f stage[4][32][64];
    __shared__ int flags[2];             // [0]=produced bufs, [1]=consumed

    const int tid   = threadIdx.x;
    const int l     = tid & 63;
    const int wave  = tid >> 6;
    const int nbase = blockIdx.x * 64;   // N % 64 == 0

    volatile int* vflags = (volatile int*)flags;
    if (tid < 2) flags[tid] = 0;
    __syncthreads();                     // once, at kernel start only

    const int NB = T >> 5;               // 32-step buffers (T % 64 == 0 -> NB even)

    if (wave == 0) {
        // ---------------- producer: the serial recurrence ----------------
        __builtin_amdgcn_s_setprio(3);   // favor the serial-chain wave

        const float V_reset = *p_V_reset;
        const float V_T     = *p_V_T;
        const float V_thres = *p_V_thres;
        const float delta_T = *p_delta_T;
        const float R       = *p_R;
        const float tau     = *p_tau;
        const float tau_w   = *p_tau_w;
        const float a       = *p_a;
        const float b       = *p_b;
        const float dt      = 5e-5f;

        // Constants folded in f64, rounded once to f32 (bit-neutral class).
        const double dT  = (double)delta_T;
        const double dcv = (double)dt / (double)tau;
        const double dcw = (double)dt / (double)tau_w;
        const double l2e = 1.4426950408889634;

        const float c_exp = (float)(l2e / dT);
        const float c2    = (float)(log2(dT * dcv) - (double)V_T * (l2e / dT));
        const float alpha = (float)(1.0 - dcv);
        const float ncRv  = (float)(-dcv * (double)R);
        const float beta  = (float)(1.0 - dcw);
        const float gamma = (float)((double)a * dcw);

        // Packed coefficient pairs for v_pk_fma_f32.
        v2f cAG; cAG.x = alpha; cAG.y = gamma;
        v2f cNB; cNB.x = ncRv;  cNB.y = beta;

        // Ping-pong packed state {V, w}. VWa = state entering the step pair.
        v2f VWa, VWb;
        VWa.x = V0[nbase + l];
        VWa.y = w0[nbase + l];

        // AD double-buffer register sets, defined only by volatile asm
        // loads -> unsinkable, guaranteed resident (R17-proven).
        u64 A[32], B[32];
        const unsigned long long adbase = (unsigned long long)ADf;

#define LDSET(ARR, VOFF)                                                  \
        {                                                                 \
            unsigned _vo = (VOFF);                                        \
            _Pragma("unroll")                                             \
            for (int j = 0; j < 32; ++j)                                  \
                asm volatile("global_load_dwordx2 %0, %1, %2 offset:%3"   \
                             : "=v"(ARR[j])                               \
                             : "v"(_vo), "s"(adbase), "n"(j * 8));        \
        }

        // One step S -> D. All fp ops value-identical to the verified R14
        // math (ping-pong is pure renaming of the old in-place tie):
        //   P1.lo = fma(alpha,S.V,Ar2)   P1.hi = fma(gamma,S.V,delta)
        //   D.lo  = fma(ncRv,S.w,P1.lo)  D.hi  = fma(beta,S.w,P1.hi)
        //   D.V  += 2^fma(S.V,c_exp,c2); unconditional spike selects
        // (NO per-step branch -- R18 lesson).
#define STEP(S, D, ADW)                                                   \
        {                                                                 \
            float u  = fmaf((S).x, c_exp, c2);                            \
            bool  sp = (S).x > V_thres;                                   \
            float ex = exp2_raw(u);                                       \
            v2f P1;                                                       \
            asm("v_pk_fma_f32 %0, %1, %2, %3 op_sel:[0,0,0] op_sel_hi:[1,0,1]" \
                : "=v"(P1) : "v"(cAG), "v"(S), "v"(ADW));                 \
            asm("v_pk_fma_f32 %0, %1, %2, %3 op_sel:[0,1,0] op_sel_hi:[1,1,1]" \
                : "=v"(D) : "v"(cNB), "v"(S), "v"(P1));                   \
            (D).x += ex;                                                  \
            float wns = (D).y + b;                                        \
            (D).x = sp ? V_reset : (D).x;                                 \
            (D).y = sp ? wns : (D).y;                                     \
        }

        // One 32-step buffer from register set ARR. vmcnt(32): newest 32
        // loads (next buffer) stay in flight; ARR resident. sched_barrier
        // per rule #18. NO LGKM0 (DS pipe in-order per wave, R19-proven).
        // Staging: ds_write2st64_b64 = both pre-states of a step pair in
        // one slot (offsets scaled by 512B = step stride).
#define PRODUCE(ARR)                                                      \
        {                                                                 \
            asm volatile("s_waitcnt vmcnt(32)");                          \
            __builtin_amdgcn_sched_barrier(0);                            \
            unsigned lds_a = (unsigned)(unsigned long long)               \
                (__attribute__((address_space(3))) void*)&stage[pi & 3][0][l]; \
            _Pragma("unroll")                                             \
            for (int s = 0; s < 16; ++s) {                                \
                STEP(VWa, VWb, ARR[2 * s]);                               \
                asm volatile("ds_write2st64_b64 %0, %1, %2 offset0:%3 offset1:%4" \
                             :: "v"(lds_a), "v"(VWa), "v"(VWb),           \
                                "n"(2 * s), "n"(2 * s + 1));              \
                STEP(VWb, VWa, ARR[2 * s + 1]);                           \
            }                                                             \
            asm volatile("" ::: "memory");                                \
            ++pi;                                                         \
            vflags[0] = pi;                                               \
        }

        // Prologue: buffer 0 into set A.
        LDSET(A, 0u);

        int pi = 0;
        unsigned voff = 0;
        while (pi < NB) {
            // Back-pressure (ring 4 deep): producing pi and pi+1 needs
            // consumed >= pi-2. Flag pre-read BEFORE the LDSET burst hides
            // the ~120cyc LDS latency; poll loop only if consumer behind.
            int fc = vflags[1];
            voff += 256;
            LDSET(B, voff);        // buffer pi+1
            if (fc < pi - 2) {
                while (vflags[1] < pi - 2) __builtin_amdgcn_s_sleep(2);
            }
            asm volatile("" ::: "memory");

            PRODUCE(A);

            voff += 256;
            LDSET(A, voff);        // buffer pi+2 (last issue reads the
                                   // (T+32)-entry AD tail; never consumed)
            PRODUCE(B);
        }
#undef PRODUCE
#undef STEP
#undef LDSET
    } else {
        // ---------------- consumer: drain LDS -> global ----------------
        float* __restrict__ outw = out + (size_t)T * N;
        unsigned idx = (unsigned)(nbase + l);      // += N per step

        for (int ci = 0; ci < NB; ++ci) {
            while (vflags[0] < ci + 1) __builtin_amdgcn_s_sleep(2);
            asm volatile("" ::: "memory");
            const v2f* cb = &stage[ci & 3][0][l];
#pragma unroll
            for (int s = 0; s < 32; ++s) {
                v2f q = cb[s * 64];
                out[idx]  = q.x;
                outw[idx] = q.y;
                idx += (unsigned)N;
            }
            // LDS reads retired (store data deps forced waits); slot free.
            asm volatile("" ::: "memory");
            vflags[1] = ci + 1;
        }
    }
}

// Fallback: R11-style single-wave kernel for shapes that don't meet the
// producer/consumer preconditions (N%64, T%64, workspace size).
__global__ void __launch_bounds__(64, 1) adex_fallback_kernel(
    const float* __restrict__ I_ext,
    const float* __restrict__ V0,
    const float* __restrict__ w0,
    const float* __restrict__ p_V_rest,
    const float* __restrict__ p_V_reset,
    const float* __restrict__ p_V_T,
    const float* __restrict__ p_V_thres,
    const float* __restrict__ p_delta_T,
    const float* __restrict__ p_R,
    const float* __restrict__ p_tau,
    const float* __restrict__ p_tau_w,
    const float* __restrict__ p_a,
    const float* __restrict__ p_b,
    float* __restrict__ out,
    int T, int N)
{
#pragma clang fp contract(off)
    const int l     = threadIdx.x;
    const int nbase = blockIdx.x * 64;
    int n = nbase + l;
    if (n >= N) n = N - 1;

    const float V_rest  = *p_V_rest;
    const float V_reset = *p_V_reset;
    const float V_T     = *p_V_T;
    const float V_thres = *p_V_thres;
    const float delta_T = *p_delta_T;
    const float R       = *p_R;
    const float tau     = *p_tau;
    const float tau_w   = *p_tau_w;
    const float a       = *p_a;
    const float b       = *p_b;
    const float dt      = 5e-5f;

    const double dT  = (double)delta_T;
    const double dcv = (double)dt / (double)tau;
    const double dcw = (double)dt / (double)tau_w;
    const double l2e = 1.4426950408889634;

    const float c_exp = (float)(l2e / dT);
    const float c2    = (float)(log2(dT * dcv) - (double)V_T * (l2e / dT));
    const float alpha = (float)(1.0 - dcv);
    const float ncRv  = (float)(-dcv * (double)R);
    const float beta  = (float)(1.0 - dcw);
    const float gamma = (float)((double)a * dcw);
    const float delta = (float)(-(double)a * dcw * (double)V_rest);
    const float cRI   = (float)(dcv * (double)R);
    const float cVr2  = (float)(dcv * (double)V_rest);

    float V = V0[n];
    float w = w0[n];

    float* outVb = out + nbase;
    float* outWb = out + (size_t)T * N + nbase;

#define ADEX_STEP(Ar2_k)                                            \
    {                                                               \
        outVb[l] = V;                                               \
        outWb[l] = w;                                               \
        outVb += N;                                                 \
        outWb += N;                                                 \
        float ex3 = exp2_raw(fmaf(V, c_exp, c2));                   \
        float m1  = fmaf(alpha, V, (Ar2_k));                        \
        float m2  = fmaf(ncRv, w, m1);                              \
        float Vn  = m2 + ex3;                                       \
        float t2  = fmaf(gamma, V, delta);                          \
        float wn  = fmaf(beta, w, t2);                              \
        bool  spike = V > V_thres;                                  \
        float wns = wn + b;                                         \
        Vn = spike ? V_reset : Vn;                                  \
        wn = spike ? wns : wn;                                      \
        V = Vn;                                                     \
        w = wn;                                                     \
    }

    float A[16], B[16];
#pragma unroll
    for (int j = 0; j < 16; ++j) A[j] = fmaf(cRI, I_ext[j], cVr2);

    for (int kb = 0; kb < T; kb += 32) {
#pragma unroll
        for (int j = 0; j < 16; ++j)
            B[j] = fmaf(cRI, I_ext[kb + 16 + j], cVr2);
#pragma unroll
        for (int j = 0; j < 16; ++j) ADEX_STEP(A[j]);
        {
            int pb = kb + 32;
            if (pb > T - 11) pb = T - 11;
#pragma unroll
            for (int j = 0; j < 16; ++j)
                A[j] = fmaf(cRI, I_ext[pb + j], cVr2);
        }
#pragma unroll
        for (int j = 0; j < 16; ++j) ADEX_STEP(B[j]);
    }
#undef ADEX_STEP
}

extern "C" void kernel_launch(void* const* d_in, const int* in_sizes, int n_in,
                              void* d_out, int out_size, void* d_ws, size_t ws_size,
                              hipStream_t stream) {
    const float* I_ext = (const float*)d_in[0];
    const float* V0    = (const float*)d_in[1];
    const float* w0    = (const float*)d_in[2];

    const int N = in_sizes[1];          // 1024 (multiple of 64)
    const int T = out_size / (2 * N);   // 40000 (multiple of 64)

    const size_t ws_need = (size_t)(T + 32) * sizeof(float2);

    if ((N % 64 == 0) && (T % 64 == 0) && d_ws != nullptr && ws_size >= ws_need) {
        adex_prep_kernel<<<(T + 32 + 255) / 256, 256, 0, stream>>>(
            I_ext,
            (const float*)d_in[3],      // V_rest
            (const float*)d_in[8],      // R
            (const float*)d_in[9],      // tau
            (const float*)d_in[10],     // tau_w
            (const float*)d_in[11],     // a
            (float2*)d_ws, T);
        adex_pc_kernel<<<N / 64, 128, 0, stream>>>(
            V0, w0,
            (const float*)d_in[4],      // V_reset
            (const float*)d_in[5],      // V_T
            (const float*)d_in[6],      // V_thres
            (const float*)d_in[7],      // delta_T
            (const float*)d_in[8],      // R
            (const float*)d_in[9],      // tau
            (const float*)d_in[10],     // tau_w
            (const float*)d_in[11],     // a
            (const float*)d_in[12],     // b
            (const float*)d_ws,
            (float*)d_out, T, N);
    } else {
        adex_fallback_kernel<<<(N + 63) / 64, 64, 0, stream>>>(
            I_ext, V0, w0,
            (const float*)d_in[3], (const float*)d_in[4], (const float*)d_in[5],
            (const float*)d_in[6], (const float*)d_in[7], (const float*)d_in[8],
            (const float*)d_in[9], (const float*)d_in[10], (const float*)d_in[11],
            (const float*)d_in[12], (float*)d_out, T, N);
    }
}

// Round 7
// 1454.500 us; speedup vs baseline: 1.3253x; 1.0796x over previous
//
#include <hip/hip_runtime.h>

// AdEx Euler integration, fp32 port of the jax/numpy reference.
// T=40000 sequential steps; N=1024 neurons -> 16 producer waves on 16 CUs.
//
// MODEL (R1-R20): lone in-order wave; wall = producer instruction stream.
// VALU dep-chain cadence ~4-5 cyc, VMEM/DS issue slots cost more (~8 cyc)
// -> stream averages ~7.1 cyc/slot at 10.5-11.3 slots/step.
// Proven-out: C-level reg prefetch arrays get SUNK (R15); AD via LDS
// serializes on lgkmcnt + bank conflicts (R16); per-step uniform branch =
// VALU->SGPR->SALU->branch hazard +18cyc/step (R18, banned; accounts for
// R18's entire regression -> its x4-load widening was never isolated).
// R17 volatile-asm load double-buffer 1354us; R19 no-LGKM0+poll-hide
// 1340us; R20 ds_write2st64_b64 pair staging + setprio(3) 1298us.
//
// R21 (this): ONE variable on top of R20 -- AD loads widened to
// global_load_dwordx4 (16/buffer instead of 32). Halves the VMEM issue
// slots (1 -> 0.5/step). v4f sub-halves are even-aligned subregs; aligned
// shufflevector extracts feeding asm "v" operands should be copy-free.
// Math DAG untouched (pk_add fusion of add_ex+add_wns examined: the
// {ex,b} pair build costs the mov it saves; v_cmpx spike trick = EXEC
// hazard of the R18 family -- both rejected).
// Predict kernel ~1230-1260us; absmax EXACTLY 4.882812e-04; conflicts 0.
// If wash (>=1285): extraction movs ate it -> x2 final, ledger exhausted.

typedef float v2f __attribute__((ext_vector_type(2)));
typedef float v4f __attribute__((ext_vector_type(4)));

__device__ __forceinline__ float exp2_raw(float u) {
    float r;
    asm("v_exp_f32 %0, %1" : "=v"(r) : "v"(u));   // r = 2^u, ~1 ulp
    return r;
}

// ---------------------------------------------------------------------------
// Prep: AD[k] = {Ar2_k, delta} for k in [0, T+32). Bit-identical constant
// folding to the producer's original in-loop computation (same f64
// expressions, rounded once to f32; same fmaf on the same I value).
// ---------------------------------------------------------------------------
__global__ void __launch_bounds__(256) adex_prep_kernel(
    const float* __restrict__ I_ext,
    const float* __restrict__ p_V_rest,
    const float* __restrict__ p_R,
    const float* __restrict__ p_tau,
    const float* __restrict__ p_tau_w,
    const float* __restrict__ p_a,
    float2* __restrict__ AD, int T)
{
#pragma clang fp contract(off)
    int k = blockIdx.x * 256 + threadIdx.x;
    if (k >= T + 32) return;

    const float V_rest = *p_V_rest;
    const float R      = *p_R;
    const float tau    = *p_tau;
    const float tau_w  = *p_tau_w;
    const float a      = *p_a;
    const float dt     = 5e-5f;

    const double dcv = (double)dt / (double)tau;
    const double dcw = (double)dt / (double)tau_w;

    const float cRI   = (float)(dcv * (double)R);
    const float cVr2  = (float)(dcv * (double)V_rest);
    const float delta = (float)(-(double)a * dcw * (double)V_rest);

    int ki = (k <= T + 4) ? k : (T + 4);      // tail entries never consumed
    AD[k] = make_float2(fmaf(cRI, I_ext[ki], cVr2), delta);
}

// ---------------------------------------------------------------------------
// Main producer/consumer kernel.
// ---------------------------------------------------------------------------
__global__ void __launch_bounds__(128, 1) adex_pc_kernel(
    const float* __restrict__ V0,
    const float* __restrict__ w0,
    const float* __restrict__ p_V_reset,
    const float* __restrict__ p_V_T,
    const float* __restrict__ p_V_thres,
    const float* __restrict__ p_delta_T,
    const float* __restrict__ p_R,
    const float* __restrict__ p_tau,
    const float* __restrict__ p_tau_w,
    const float* __restrict__ p_a,
    const float* __restrict__ p_b,
    const float* __restrict__ ADf,       // workspace: {Ar2,delta} pairs
    float* __restrict__ out,
    int T, int N)
{
#pragma clang fp contract(off)
    // Ring of 4 buffers x 32 steps x 64 lanes x float2 = 64 KiB.
    // [buf][step][lane]: lane stride 8B (conflict-free, measured 0);
    // step stride 512B = the ds_*st64 b64 unit.
    __shared__ v2f stage[4][32][64];
    __shared__ int flags[2];             // [0]=produced bufs, [1]=consumed

    const int tid   = threadIdx.x;
    const int l     = tid & 63;
    const int wave  = tid >> 6;
    const int nbase = blockIdx.x * 64;   // N % 64 == 0

    volatile int* vflags = (volatile int*)flags;
    if (tid < 2) flags[tid] = 0;
    __syncthreads();                     // once, at kernel start only

    const int NB = T >> 5;               // 32-step buffers (T % 64 == 0 -> NB even)

    if (wave == 0) {
        // ---------------- producer: the serial recurrence ----------------
        __builtin_amdgcn_s_setprio(3);   // favor the serial-chain wave

        const float V_reset = *p_V_reset;
        const float V_T     = *p_V_T;
        const float V_thres = *p_V_thres;
        const float delta_T = *p_delta_T;
        const float R       = *p_R;
        const float tau     = *p_tau;
        const float tau_w   = *p_tau_w;
        const float a       = *p_a;
        const float b       = *p_b;
        const float dt      = 5e-5f;

        // Constants folded in f64, rounded once to f32 (bit-neutral class).
        const double dT  = (double)delta_T;
        const double dcv = (double)dt / (double)tau;
        const double dcw = (double)dt / (double)tau_w;
        const double l2e = 1.4426950408889634;

        const float c_exp = (float)(l2e / dT);
        const float c2    = (float)(log2(dT * dcv) - (double)V_T * (l2e / dT));
        const float alpha = (float)(1.0 - dcv);
        const float ncRv  = (float)(-dcv * (double)R);
        const float beta  = (float)(1.0 - dcw);
        const float gamma = (float)((double)a * dcw);

        // Packed coefficient pairs for v_pk_fma_f32.
        v2f cAG; cAG.x = alpha; cAG.y = gamma;
        v2f cNB; cNB.x = ncRv;  cNB.y = beta;

        // Ping-pong packed state {V, w}. VWa = state entering the step pair.
        v2f VWa, VWb;
        VWa.x = V0[nbase + l];
        VWa.y = w0[nbase + l];

        // AD double-buffer register sets (16 quads = 64 VGPR each), defined
        // only by volatile asm loads -> unsinkable, guaranteed resident.
        v4f A4[16], B4[16];
        const unsigned long long adbase = (unsigned long long)ADf;

#define LDSET(ARR, VOFF)                                                  \
        {                                                                 \
            unsigned _vo = (VOFF);                                        \
            _Pragma("unroll")                                             \
            for (int j = 0; j < 16; ++j)                                  \
                asm volatile("global_load_dwordx4 %0, %1, %2 offset:%3"   \
                             : "=v"(ARR[j])                               \
                             : "v"(_vo), "s"(adbase), "n"(j * 16));       \
        }

        // One step S -> D. All fp ops value-identical to the verified R14
        // math (ping-pong = pure renaming):
        //   P1.lo = fma(alpha,S.V,Ar2)   P1.hi = fma(gamma,S.V,delta)
        //   D.lo  = fma(ncRv,S.w,P1.lo)  D.hi  = fma(beta,S.w,P1.hi)
        //   D.V  += 2^fma(S.V,c_exp,c2); unconditional spike selects
        // (NO per-step branch -- R18 lesson).
#define STEP(S, D, ADW)                                                   \
        {                                                                 \
            float u  = fmaf((S).x, c_exp, c2);                            \
            bool  sp = (S).x > V_thres;                                   \
            float ex = exp2_raw(u);                                       \
            v2f P1;                                                       \
            asm("v_pk_fma_f32 %0, %1, %2, %3 op_sel:[0,0,0] op_sel_hi:[1,0,1]" \
                : "=v"(P1) : "v"(cAG), "v"(S), "v"(ADW));                 \
            asm("v_pk_fma_f32 %0, %1, %2, %3 op_sel:[0,1,0] op_sel_hi:[1,1,1]" \
                : "=v"(D) : "v"(cNB), "v"(S), "v"(P1));                   \
            (D).x += ex;                                                  \
            float wns = (D).y + b;                                        \
            (D).x = sp ? V_reset : (D).x;                                 \
            (D).y = sp ? wns : (D).y;                                     \
        }

        // One 32-step buffer from register set ARR. vmcnt(16): newest 16
        // loads (next buffer) stay in flight; ARR resident. sched_barrier
        // per rule #18. NO LGKM0 (DS pipe in-order per wave, R19-proven).
        // Staging: ds_write2st64_b64 = both pre-states of a step pair in
        // one slot (offsets scaled by 512B = step stride).
#define PRODUCE(ARR)                                                      \
        {                                                                 \
            asm volatile("s_waitcnt vmcnt(16)");                          \
            __builtin_amdgcn_sched_barrier(0);                            \
            unsigned lds_a = (unsigned)(unsigned long long)               \
                (__attribute__((address_space(3))) void*)&stage[pi & 3][0][l]; \
            _Pragma("unroll")                                             \
            for (int s = 0; s < 16; ++s) {                                \
                v4f q = ARR[s];                                           \
                v2f ad0 = __builtin_shufflevector(q, q, 0, 1);            \
                v2f ad1 = __builtin_shufflevector(q, q, 2, 3);            \
                STEP(VWa, VWb, ad0);                                      \
                asm volatile("ds_write2st64_b64 %0, %1, %2 offset0:%3 offset1:%4" \
                             :: "v"(lds_a), "v"(VWa), "v"(VWb),           \
                                "n"(2 * s), "n"(2 * s + 1));              \
                STEP(VWb, VWa, ad1);                                      \
            }                                                             \
            asm volatile("" ::: "memory");                                \
            ++pi;                                                         \
            vflags[0] = pi;                                               \
        }

        // Prologue: buffer 0 into set A.
        LDSET(A4, 0u);

        int pi = 0;
        unsigned voff = 0;
        while (pi < NB) {
            // Back-pressure (ring 4 deep): producing pi and pi+1 needs
            // consumed >= pi-2. Flag pre-read BEFORE the LDSET burst hides
            // the ~120cyc LDS latency; poll loop only if consumer behind.
            int fc = vflags[1];
            voff += 256;
            LDSET(B4, voff);       // buffer pi+1
            if (fc < pi - 2) {
                while (vflags[1] < pi - 2) __builtin_amdgcn_s_sleep(2);
            }
            asm volatile("" ::: "memory");

            PRODUCE(A4);

            voff += 256;
            LDSET(A4, voff);       // buffer pi+2 (last issue reads the
                                   // (T+32)-entry AD tail; never consumed)
            PRODUCE(B4);
        }
#undef PRODUCE
#undef STEP
#undef LDSET
    } else {
        // ---------------- consumer: drain LDS -> global ----------------
        float* __restrict__ outw = out + (size_t)T * N;
        unsigned idx = (unsigned)(nbase + l);      // += N per step

        for (int ci = 0; ci < NB; ++ci) {
            while (vflags[0] < ci + 1) __builtin_amdgcn_s_sleep(2);
            asm volatile("" ::: "memory");
            const v2f* cb = &stage[ci & 3][0][l];
#pragma unroll
            for (int s = 0; s < 32; ++s) {
                v2f q = cb[s * 64];
                out[idx]  = q.x;
                outw[idx] = q.y;
                idx += (unsigned)N;
            }
            // LDS reads retired (store data deps forced waits); slot free.
            asm volatile("" ::: "memory");
            vflags[1] = ci + 1;
        }
    }
}

// Fallback: R11-style single-wave kernel for shapes that don't meet the
// producer/consumer preconditions (N%64, T%64, workspace size).
__global__ void __launch_bounds__(64, 1) adex_fallback_kernel(
    const float* __restrict__ I_ext,
    const float* __restrict__ V0,
    const float* __restrict__ w0,
    const float* __restrict__ p_V_rest,
    const float* __restrict__ p_V_reset,
    const float* __restrict__ p_V_T,
    const float* __restrict__ p_V_thres,
    const float* __restrict__ p_delta_T,
    const float* __restrict__ p_R,
    const float* __restrict__ p_tau,
    const float* __restrict__ p_tau_w,
    const float* __restrict__ p_a,
    const float* __restrict__ p_b,
    float* __restrict__ out,
    int T, int N)
{
#pragma clang fp contract(off)
    const int l     = threadIdx.x;
    const int nbase = blockIdx.x * 64;
    int n = nbase + l;
    if (n >= N) n = N - 1;

    const float V_rest  = *p_V_rest;
    const float V_reset = *p_V_reset;
    const float V_T     = *p_V_T;
    const float V_thres = *p_V_thres;
    const float delta_T = *p_delta_T;
    const float R       = *p_R;
    const float tau     = *p_tau;
    const float tau_w   = *p_tau_w;
    const float a       = *p_a;
    const float b       = *p_b;
    const float dt      = 5e-5f;

    const double dT  = (double)delta_T;
    const double dcv = (double)dt / (double)tau;
    const double dcw = (double)dt / (double)tau_w;
    const double l2e = 1.4426950408889634;

    const float c_exp = (float)(l2e / dT);
    const float c2    = (float)(log2(dT * dcv) - (double)V_T * (l2e / dT));
    const float alpha = (float)(1.0 - dcv);
    const float ncRv  = (float)(-dcv * (double)R);
    const float beta  = (float)(1.0 - dcw);
    const float gamma = (float)((double)a * dcw);
    const float delta = (float)(-(double)a * dcw * (double)V_rest);
    const float cRI   = (float)(dcv * (double)R);
    const float cVr2  = (float)(dcv * (double)V_rest);

    float V = V0[n];
    float w = w0[n];

    float* outVb = out + nbase;
    float* outWb = out + (size_t)T * N + nbase;

#define ADEX_STEP(Ar2_k)                                            \
    {                                                               \
        outVb[l] = V;                                               \
        outWb[l] = w;                                               \
        outVb += N;                                                 \
        outWb += N;                                                 \
        float ex3 = exp2_raw(fmaf(V, c_exp, c2));                   \
        float m1  = fmaf(alpha, V, (Ar2_k));                        \
        float m2  = fmaf(ncRv, w, m1);                              \
        float Vn  = m2 + ex3;                                       \
        float t2  = fmaf(gamma, V, delta);                          \
        float wn  = fmaf(beta, w, t2);                              \
        bool  spike = V > V_thres;                                  \
        float wns = wn + b;                                         \
        Vn = spike ? V_reset : Vn;                                  \
        wn = spike ? wns : wn;                                      \
        V = Vn;                                                     \
        w = wn;                                                     \
    }

    float A[16], B[16];
#pragma unroll
    for (int j = 0; j < 16; ++j) A[j] = fmaf(cRI, I_ext[j], cVr2);

    for (int kb = 0; kb < T; kb += 32) {
#pragma unroll
        for (int j = 0; j < 16; ++j)
            B[j] = fmaf(cRI, I_ext[kb + 16 + j], cVr2);
#pragma unroll
        for (int j = 0; j < 16; ++j) ADEX_STEP(A[j]);
        {
            int pb = kb + 32;
            if (pb > T - 11) pb = T - 11;
#pragma unroll
            for (int j = 0; j < 16; ++j)
                A[j] = fmaf(cRI, I_ext[pb + j], cVr2);
        }
#pragma unroll
        for (int j = 0; j < 16; ++j) ADEX_STEP(B[j]);
    }
#undef ADEX_STEP
}

extern "C" void kernel_launch(void* const* d_in, const int* in_sizes, int n_in,
                              void* d_out, int out_size, void* d_ws, size_t ws_size,
                              hipStream_t stream) {
    const float* I_ext = (const float*)d_in[0];
    const float* V0    = (const float*)d_in[1];
    const float* w0    = (const float*)d_in[2];

    const int N = in_sizes[1];          // 1024 (multiple of 64)
    const int T = out_size / (2 * N);   // 40000 (multiple of 64)

    const size_t ws_need = (size_t)(T + 32) * sizeof(float2);

    if ((N % 64 == 0) && (T % 64 == 0) && d_ws != nullptr && ws_size >= ws_need) {
        adex_prep_kernel<<<(T + 32 + 255) / 256, 256, 0, stream>>>(
            I_ext,
            (const float*)d_in[3],      // V_rest
            (const float*)d_in[8],      // R
            (const float*)d_in[9],      // tau
            (const float*)d_in[10],     // tau_w
            (const float*)d_in[11],     // a
            (float2*)d_ws, T);
        adex_pc_kernel<<<N / 64, 128, 0, stream>>>(
            V0, w0,
            (const float*)d_in[4],      // V_reset
            (const float*)d_in[5],      // V_T
            (const float*)d_in[6],      // V_thres
            (const float*)d_in[7],      // delta_T
            (const float*)d_in[8],      // R
            (const float*)d_in[9],      // tau
            (const float*)d_in[10],     // tau_w
            (const float*)d_in[11],     // a
            (const float*)d_in[12],     // b
            (const float*)d_ws,
            (float*)d_out, T, N);
    } else {
        adex_fallback_kernel<<<(N + 63) / 64, 64, 0, stream>>>(
            I_ext, V0, w0,
            (const float*)d_in[3], (const float*)d_in[4], (const float*)d_in[5],
            (const float*)d_in[6], (const float*)d_in[7], (const float*)d_in[8],
            (const float*)d_in[9], (const float*)d_in[10], (const float*)d_in[11],
            (const float*)d_in[12], (float*)d_out, T, N);
    }
}